// Round 1
// baseline (24213.451 us; speedup 1.0000x reference)
//
#include <hip/hip_runtime.h>
#include <hip/hip_bf16.h>

typedef __bf16 bf16x8 __attribute__((ext_vector_type(8)));
typedef float f32x4 __attribute__((ext_vector_type(4)));

#define DEV static __device__ __forceinline__

constexpr int Bq = 32, Sq = 128, Tq = 64, Eq = 256, Hq = 512, Vq = 32000;
constexpr int G4 = 2048;          // 4*H
constexpr int TD = 63;            // decode steps (T-1)
constexpr int KOUT = 1280;        // 2H + E
constexpr float SQRTE = 16.0f;    // sqrt(256)

DEV float sigf(float x) { return 1.0f / (1.0f + __expf(-x)); }

// ---------------- embeddings ----------------
__global__ __launch_bounds__(256) void k_embed_src(const int* __restrict__ tok,
                                                   const float* __restrict__ emb,
                                                   float* __restrict__ x)
{
    int idx = blockIdx.x * 256 + threadIdx.x;     // S*B*E = 1048576
    int e = idx & (Eq - 1);
    int r = idx >> 8;                             // t*32 + b
    int b = r & 31, t = r >> 5;
    x[idx] = emb[(size_t)tok[b * Sq + t] * Eq + e] * SQRTE;
}

__global__ __launch_bounds__(256) void k_embed_tgt(const int* __restrict__ tok,
                                                   const float* __restrict__ emb,
                                                   float* __restrict__ embt,
                                                   __hip_bfloat16* __restrict__ Xout)
{
    int idx = blockIdx.x * 256 + threadIdx.x;     // 63*32*256 = 516096
    int e = idx & (Eq - 1);
    int r = idx >> 8;                             // t*32 + b
    int b = r & 31, t = r >> 5;
    float v = fmaxf(0.f, emb[(size_t)tok[b * Tq + t] * Eq + e] * SQRTE);
    embt[idx] = v;
    Xout[(size_t)r * KOUT + 1024 + e] = __float2bfloat16(v);
}

// ---------------- generic f32 GEMM: C = A@W (+bias) ----------------
// grid (N/64, ceil(M/64)), block 256. Each thread: one n, 16 m's.
__global__ __launch_bounds__(256) void k_gemm16(const float* __restrict__ A,
                                                const float* __restrict__ W,
                                                const float* __restrict__ bias,
                                                float* __restrict__ C,
                                                int M, int N, int K)
{
    __shared__ float As[64][33];
    int n0 = blockIdx.x * 64, m0 = blockIdx.y * 64;
    int tx = threadIdx.x;
    int n = n0 + (tx & 63), wv = tx >> 6;
    float acc[16];
#pragma unroll
    for (int i = 0; i < 16; i++) acc[i] = 0.f;
    for (int k0 = 0; k0 < K; k0 += 32) {
        __syncthreads();
#pragma unroll
        for (int p = 0; p < 8; p++) {
            int idx = tx + p * 256; int r = idx >> 5, kk = idx & 31;
            int m = m0 + r;
            As[r][kk] = (m < M) ? A[(size_t)m * K + k0 + kk] : 0.f;
        }
        __syncthreads();
#pragma unroll 8
        for (int k = 0; k < 32; k++) {
            float wval = W[(size_t)(k0 + k) * N + n];
#pragma unroll
            for (int i = 0; i < 16; i++) acc[i] += As[wv * 16 + i][k] * wval;
        }
    }
    float bv = bias ? bias[n] : 0.f;
#pragma unroll
    for (int i = 0; i < 16; i++) {
        int m = m0 + wv * 16 + i;
        if (m < M) C[(size_t)m * N + n] = acc[i] + bv;
    }
}

// ---------------- transpose + cast out_W (K x N) -> Wt (N x K) bf16 ----------------
__global__ __launch_bounds__(256) void k_transpose_bf16(const float* __restrict__ W,
                                                        __hip_bfloat16* __restrict__ Wt,
                                                        int K, int N)
{
    __shared__ float tile[32][33];
    int nb = blockIdx.x * 32, kb = blockIdx.y * 32;
    int c = threadIdx.x & 31, r4 = threadIdx.x >> 5;   // 8 rows per pass
    for (int i = 0; i < 32; i += 8)
        tile[r4 + i][c] = W[(size_t)(kb + r4 + i) * N + nb + c];
    __syncthreads();
    for (int i = 0; i < 32; i += 8) {
        int rr = r4 + i;
        Wt[(size_t)(nb + rr) * K + kb + c] = __float2bfloat16(tile[c][rr]);
    }
}

// ---------------- encoder: pipelined dual-layer step ----------------
// blocks 0..255: layer0 step t (if t<128); blocks 256..511: layer1 step t-1 (if t>=1)
__global__ __launch_bounds__(256) void k_enc_dual(int t,
    const float* __restrict__ X0, const float* __restrict__ Whh0,
    const float* __restrict__ Wih1, const float* __restrict__ Whh1,
    const float* __restrict__ b1,
    float* __restrict__ h0d, float* __restrict__ h1d,
    float* __restrict__ c0, float* __restrict__ c1,
    float* __restrict__ ys0, float* __restrict__ enc_out)
{
    __shared__ float s0[4][520];
    __shared__ float s1[4][520];
    __shared__ float gx[4][64];
    int bi = blockIdx.x;
    bool lay1 = bi >= 256;
    if (!lay1 && t >= 128) return;
    if (lay1 && t < 1) return;
    int bb = lay1 ? bi - 256 : bi;
    int s = lay1 ? t - 1 : t;
    int bt = bb & 7, jt = bb >> 3;
    int b0 = bt * 4, j0 = jt * 16;
    int tx = threadIdx.x;
    const float* hprev = (lay1 ? h1d : h0d) + (s & 1) * 16384;
#pragma unroll
    for (int p = 0; p < 8; p++) {
        int idx = tx + p * 256; int r = idx >> 9, k = idx & 511;
        if (lay1) {
            s0[r][k] = ys0[((size_t)s * 32 + b0 + r) * 512 + k];
            s1[r][k] = hprev[(b0 + r) * 512 + k];
        } else {
            s0[r][k] = hprev[(b0 + r) * 512 + k];
        }
    }
    __syncthreads();
    int g = tx >> 6, lane = tx & 63, bl = lane >> 4, jl = lane & 15;
    int col = g * 512 + j0 + jl;
    float acc;
    if (!lay1) {
        acc = X0[((size_t)t * 32 + b0 + bl) * G4 + col];
        const float* wp = Whh0 + col;
#pragma unroll 8
        for (int k = 0; k < 512; k++) acc += s0[bl][k] * wp[(size_t)k * G4];
    } else {
        acc = b1[col];
        const float* wp0 = Wih1 + col;
        const float* wp1 = Whh1 + col;
#pragma unroll 4
        for (int k = 0; k < 512; k++) {
            acc += s0[bl][k] * wp0[(size_t)k * G4];
            acc += s1[bl][k] * wp1[(size_t)k * G4];
        }
    }
    gx[g][lane] = acc;
    __syncthreads();
    if (tx < 64) {
        int bl2 = tx >> 4, jl2 = tx & 15;
        int b = b0 + bl2, j = j0 + jl2, ci = b * 512 + j;
        float* cp = lay1 ? c1 : c0;
        float cc = cp[ci];
        float cn = sigf(gx[1][tx]) * cc + sigf(gx[0][tx]) * tanhf(gx[2][tx]);
        cp[ci] = cn;
        float hn = sigf(gx[3][tx]) * tanhf(cn);
        (lay1 ? h1d : h0d)[((s + 1) & 1) * 16384 + ci] = hn;
        if (!lay1) ys0[((size_t)s * 32 + b) * 512 + j] = hn;
        else       enc_out[((size_t)b * 128 + s) * 512 + j] = hn;
    }
}

// ---------------- decoder attention (one block per batch row) ----------------
__global__ __launch_bounds__(256) void k_dec_attn(
    const float* __restrict__ h0cur, const float* __restrict__ h1cur,
    const float* __restrict__ attn_W, const float* __restrict__ attn_b,
    const float* __restrict__ v_w, const float* __restrict__ coal_w,
    const float* __restrict__ coal_b,
    const float* __restrict__ enc_proj, const float* __restrict__ enc_out,
    const int* __restrict__ src_tok,
    float* __restrict__ wctx, __hip_bfloat16* __restrict__ Xout)
{
    __shared__ float q[512];
    __shared__ float aq[512];
    __shared__ float sc[128];
    int b = blockIdx.x;
    int tx = threadIdx.x;
    float cw0 = coal_w[0], cw1 = coal_w[1], cb = coal_b[0];
    // q[b,j] = relu(hflat[b*1024+2j]*cw0 + hflat[b*1024+2j+1]*cw1 + cb)
    for (int j = tx; j < 512; j += 256) {
        int p = b * 1024 + 2 * j;
        float v0 = (p < 16384) ? h0cur[p] : h1cur[p - 16384];
        float v1 = (p + 1 < 16384) ? h0cur[p + 1] : h1cur[p + 1 - 16384];
        q[j] = fmaxf(0.f, v0 * cw0 + v1 * cw1 + cb);
    }
    __syncthreads();
    // attq = q @ Wq + attn_b
    for (int i = tx; i < 512; i += 256) {
        float a = attn_b[i];
#pragma unroll 8
        for (int j = 0; j < 512; j++) a += q[j] * attn_W[(size_t)j * 512 + i];
        aq[i] = a;
    }
    __syncthreads();
    // scores: wave wv handles s = wv, wv+4, ...
    int wv = tx >> 6, lane = tx & 63;
    for (int s = wv; s < 128; s += 4) {
        const float* ep = enc_proj + ((size_t)b * 128 + s) * 512;
        float p = 0.f;
#pragma unroll
        for (int i = lane; i < 512; i += 64)
            p += tanhf(ep[i] + aq[i]) * v_w[i];
#pragma unroll
        for (int o = 32; o > 0; o >>= 1) p += __shfl_down(p, o, 64);
        if (lane == 0)
            sc[s] = (src_tok[b * 128 + s] != 1) ? p : -1e10f;
    }
    __syncthreads();
    // softmax over 128 (wave 0)
    if (tx < 64) {
        float m1 = fmaxf(sc[tx], sc[tx + 64]);
#pragma unroll
        for (int o = 32; o > 0; o >>= 1) m1 = fmaxf(m1, __shfl_down(m1, o, 64));
        m1 = __shfl(m1, 0, 64);
        float e0 = __expf(sc[tx] - m1), e1 = __expf(sc[tx + 64] - m1);
        float ss = e0 + e1;
#pragma unroll
        for (int o = 32; o > 0; o >>= 1) ss += __shfl_down(ss, o, 64);
        ss = __shfl(ss, 0, 64);
        float inv = 1.0f / ss;
        sc[tx] = e0 * inv; sc[tx + 64] = e1 * inv;
    }
    __syncthreads();
    // wctx = a @ enc_out
    for (int i = tx; i < 512; i += 256) {
        float w = 0.f;
#pragma unroll 8
        for (int s = 0; s < 128; s++)
            w += sc[s] * enc_out[((size_t)b * 128 + s) * 512 + i];
        wctx[b * 512 + i] = w;
        Xout[(size_t)b * KOUT + 512 + i] = __float2bfloat16(w);
    }
}

// ---------------- decoder LSTM gates + cell ----------------
// gates = xpart(or bias) + in0@W0 + in1@W1; then cell update.
__global__ __launch_bounds__(256) void k_dec_gates(
    const float* __restrict__ in0, const float* __restrict__ in1,
    const float* __restrict__ W0, const float* __restrict__ W1,
    const float* __restrict__ xpart, const float* __restrict__ bias,
    float* __restrict__ cbuf, float* __restrict__ hout,
    __hip_bfloat16* __restrict__ Xout)
{
    __shared__ float s0[4][520];
    __shared__ float s1[4][520];
    __shared__ float gx[4][64];
    int bi = blockIdx.x;
    int bt = bi & 7, jt = bi >> 3;
    int b0 = bt * 4, j0 = jt * 16;
    int tx = threadIdx.x;
#pragma unroll
    for (int p = 0; p < 8; p++) {
        int idx = tx + p * 256; int r = idx >> 9, k = idx & 511;
        s0[r][k] = in0[(b0 + r) * 512 + k];
        s1[r][k] = in1[(b0 + r) * 512 + k];
    }
    __syncthreads();
    int g = tx >> 6, lane = tx & 63, bl = lane >> 4, jl = lane & 15;
    int col = g * 512 + j0 + jl;
    float acc = xpart ? xpart[(b0 + bl) * G4 + col] : bias[col];
    const float* w0 = W0 + col;
    const float* w1 = W1 + col;
#pragma unroll 4
    for (int k = 0; k < 512; k++) {
        acc += s0[bl][k] * w0[(size_t)k * G4];
        acc += s1[bl][k] * w1[(size_t)k * G4];
    }
    gx[g][lane] = acc;
    __syncthreads();
    if (tx < 64) {
        int bl2 = tx >> 4, jl2 = tx & 15;
        int b = b0 + bl2, j = j0 + jl2, ci = b * 512 + j;
        float cc = cbuf[ci];
        float cn = sigf(gx[1][tx]) * cc + sigf(gx[0][tx]) * tanhf(gx[2][tx]);
        cbuf[ci] = cn;
        float hn = sigf(gx[3][tx]) * tanhf(cn);
        hout[ci] = hn;
        if (Xout) Xout[(size_t)b * KOUT + j] = __float2bfloat16(hn);
    }
}

// ---------------- small copy / fill kernels ----------------
__global__ __launch_bounds__(256) void k_init_dec(
    const float* __restrict__ h0e, const float* __restrict__ h1e,
    const float* __restrict__ c0e, const float* __restrict__ c1e,
    float* __restrict__ h0d, float* __restrict__ h1d,
    float* __restrict__ c0d, float* __restrict__ c1d)
{
    int idx = blockIdx.x * 256 + threadIdx.x;     // 16384
    h0d[idx] = h0e[idx];
    h1d[idx] = h1e[idx];
    c0d[idx] = c0e[idx];
    c1d[idx] = c1e[idx];
}

__global__ __launch_bounds__(256) void k_bos(float* __restrict__ out)
{
    int b = blockIdx.y;
    int i = blockIdx.x * 256 + threadIdx.x;       // 32000
    out[(size_t)b * (Tq * Vq) + i] = 2.0f;        // BOS_IDX
}

__global__ __launch_bounds__(256) void k_finalize(
    const float* __restrict__ h0f, const float* __restrict__ h1f,
    const float* __restrict__ c0f, const float* __restrict__ c1f,
    float* __restrict__ out)
{
    int idx = blockIdx.x * 256 + threadIdx.x;     // 16384
    size_t base = (size_t)Bq * Tq * Vq;           // 65,536,000
    out[base + idx] = h0f[idx];
    out[base + 16384 + idx] = h1f[idx];
    out[base + 32768 + idx] = c0f[idx];
    out[base + 49152 + idx] = c1f[idx];
}

// ---------------- bf16 MFMA logits GEMM ----------------
// A: (2016 x 1280) bf16 row-major; Bt: (32000 x 1280) bf16 (out_W transposed)
// out: scatter to d_out[b][t+1][v] with R = t*32+b; bias = out_b
__global__ __launch_bounds__(256) void k_logits(
    const __hip_bfloat16* __restrict__ A, const __hip_bfloat16* __restrict__ Bt,
    const float* __restrict__ bias, float* __restrict__ out)
{
    __shared__ __bf16 As[128][72];
    __shared__ __bf16 Bs[128][72];
    const unsigned short* Aw = (const unsigned short*)A;
    const unsigned short* Bw = (const unsigned short*)Bt;
    int n0 = blockIdx.x * 128, m0 = blockIdx.y * 128;
    int tx = threadIdx.x;
    int w = tx >> 6, lane = tx & 63;
    int wm = (w >> 1) * 64, wn = (w & 1) * 64;
    int fr = lane & 15, kg = lane >> 4;
    f32x4 acc[4][4];
#pragma unroll
    for (int mi = 0; mi < 4; mi++)
#pragma unroll
        for (int ni = 0; ni < 4; ni++) acc[mi][ni] = (f32x4){0.f, 0.f, 0.f, 0.f};

    for (int k0 = 0; k0 < 1280; k0 += 64) {
        __syncthreads();
#pragma unroll
        for (int p = 0; p < 4; p++) {
            int ch = tx + p * 256;               // 1024 chunks of 8 bf16
            int r = ch >> 3, cc = (ch & 7) * 8;
            uint4 va = {0u, 0u, 0u, 0u};
            int m = m0 + r;
            if (m < 2016) va = *(const uint4*)(Aw + (size_t)m * 1280 + k0 + cc);
            *(uint4*)(&As[r][cc]) = va;
            uint4 vb = *(const uint4*)(Bw + (size_t)(n0 + r) * 1280 + k0 + cc);
            *(uint4*)(&Bs[r][cc]) = vb;
        }
        __syncthreads();
#pragma unroll
        for (int kk = 0; kk < 64; kk += 32) {
            bf16x8 af[4], bfv[4];
#pragma unroll
            for (int i = 0; i < 4; i++) {
                af[i]  = *(const bf16x8*)(&As[wm + i * 16 + fr][kk + kg * 8]);
                bfv[i] = *(const bf16x8*)(&Bs[wn + i * 16 + fr][kk + kg * 8]);
            }
#pragma unroll
            for (int mi = 0; mi < 4; mi++)
#pragma unroll
                for (int ni = 0; ni < 4; ni++)
                    acc[mi][ni] = __builtin_amdgcn_mfma_f32_16x16x32_bf16(
                        af[mi], bfv[ni], acc[mi][ni], 0, 0, 0);
        }
    }
#pragma unroll
    for (int ni = 0; ni < 4; ni++) {
        int n = n0 + wn + ni * 16 + fr;
        float bv = bias[n];
#pragma unroll
        for (int mi = 0; mi < 4; mi++) {
#pragma unroll
            for (int qd = 0; qd < 4; qd++) {
                int R = m0 + wm + mi * 16 + kg * 4 + qd;
                if (R < 2016) {
                    int bb = R & 31, ts = R >> 5;
                    out[(size_t)bb * (Tq * Vq) + (size_t)(ts + 1) * Vq + n] =
                        acc[mi][ni][qd] + bv;
                }
            }
        }
    }
}

// ---------------- launcher ----------------
extern "C" void kernel_launch(void* const* d_in, const int* in_sizes, int n_in,
                              void* d_out, int out_size, void* d_ws, size_t ws_size,
                              hipStream_t stream)
{
    (void)in_sizes; (void)n_in; (void)out_size; (void)ws_size;
    const int*   src_tok = (const int*)  d_in[0];
    const int*   tgt_tok = (const int*)  d_in[1];
    const float* src_emb = (const float*)d_in[2];
    const float* tgt_emb = (const float*)d_in[3];
    const float* eWih0   = (const float*)d_in[4];
    const float* eWhh0   = (const float*)d_in[5];
    const float* eb0     = (const float*)d_in[6];
    const float* eWih1   = (const float*)d_in[7];
    const float* eWhh1   = (const float*)d_in[8];
    const float* eb1     = (const float*)d_in[9];
    const float* dWih0   = (const float*)d_in[10];
    const float* dWhh0   = (const float*)d_in[11];
    const float* db0     = (const float*)d_in[12];
    const float* dWih1   = (const float*)d_in[13];
    const float* dWhh1   = (const float*)d_in[14];
    const float* db1     = (const float*)d_in[15];
    const float* attn_W  = (const float*)d_in[16];
    const float* attn_b  = (const float*)d_in[17];
    const float* v_w     = (const float*)d_in[18];
    const float* coal_w  = (const float*)d_in[19];
    const float* coal_b  = (const float*)d_in[20];
    const float* out_W   = (const float*)d_in[21];
    const float* out_b   = (const float*)d_in[22];
    float* out = (float*)d_out;

    char* ws = (char*)d_ws;
    size_t off = 0;
    auto alloc = [&](size_t bytes) -> char* {
        char* p = ws + off;
        off += (bytes + 255) & ~(size_t)255;
        return p;
    };
    float* x_src    = (float*)alloc(4096ull * 256 * 4);
    float* X0       = (float*)alloc(4096ull * 2048 * 4);
    float* ys0      = (float*)alloc(4096ull * 512 * 4);
    float* enc_out  = (float*)alloc(4096ull * 512 * 4);
    float* enc_proj = (float*)alloc(4096ull * 512 * 4);
    float* embt     = (float*)alloc(2016ull * 256 * 4);
    float* Xemb     = (float*)alloc(2016ull * 2048 * 4);
    float* wctx     = (float*)alloc(16384ull * 4);
    float* h0e      = (float*)alloc(32768ull * 4);
    float* h1e      = (float*)alloc(32768ull * 4);
    float* c0e      = (float*)alloc(16384ull * 4);
    float* c1e      = (float*)alloc(16384ull * 4);
    float* h0d      = (float*)alloc(32768ull * 4);
    float* h1d      = (float*)alloc(32768ull * 4);
    float* c0d      = (float*)alloc(16384ull * 4);
    float* c1d      = (float*)alloc(16384ull * 4);
    __hip_bfloat16* Xout = (__hip_bfloat16*)alloc(2016ull * 1280 * 2);
    __hip_bfloat16* Wt   = (__hip_bfloat16*)alloc(32000ull * 1280 * 2);

    hipMemsetAsync(h0e, 0, 32768 * 4, stream);
    hipMemsetAsync(h1e, 0, 32768 * 4, stream);
    hipMemsetAsync(c0e, 0, 16384 * 4, stream);
    hipMemsetAsync(c1e, 0, 16384 * 4, stream);

    k_embed_src<<<4096, 256, 0, stream>>>(src_tok, src_emb, x_src);
    k_gemm16<<<dim3(2048 / 64, 4096 / 64), 256, 0, stream>>>(x_src, eWih0, eb0, X0, 4096, 2048, 256);
    for (int t = 0; t <= 128; ++t)
        k_enc_dual<<<512, 256, 0, stream>>>(t, X0, eWhh0, eWih1, eWhh1, eb1,
                                            h0e, h1e, c0e, c1e, ys0, enc_out);
    k_gemm16<<<dim3(512 / 64, 4096 / 64), 256, 0, stream>>>(enc_out, attn_W + 512 * 512, nullptr,
                                                            enc_proj, 4096, 512, 512);
    k_embed_tgt<<<2016, 256, 0, stream>>>(tgt_tok, tgt_emb, embt, Xout);
    k_gemm16<<<dim3(2048 / 64, 32), 256, 0, stream>>>(embt, dWih0, db0, Xemb, 2016, 2048, 256);
    k_transpose_bf16<<<dim3(1000, 40), 256, 0, stream>>>(out_W, Wt, 1280, 32000);
    k_init_dec<<<64, 256, 0, stream>>>(h0e, h1e, c0e, c1e, h0d, h1d, c0d, c1d);
    k_bos<<<dim3(125, 32), 256, 0, stream>>>(out);

    for (int t = 0; t < TD; ++t) {
        const float* h0cur = h0d + (t & 1) * 16384;
        const float* h1cur = h1d + (t & 1) * 16384;
        float* h0nxt = h0d + ((t + 1) & 1) * 16384;
        float* h1nxt = h1d + ((t + 1) & 1) * 16384;
        __hip_bfloat16* XoutT = Xout + (size_t)t * 32 * KOUT;
        k_dec_attn<<<32, 256, 0, stream>>>(h0cur, h1cur, attn_W, attn_b, v_w, coal_w, coal_b,
                                           enc_proj, enc_out, src_tok, wctx, XoutT);
        k_dec_gates<<<256, 256, 0, stream>>>(wctx, h0cur, dWih0 + 256 * 2048, dWhh0,
                                             Xemb + (size_t)t * 32 * 2048, nullptr,
                                             c0d, h0nxt, nullptr);
        k_dec_gates<<<256, 256, 0, stream>>>(h0nxt, h1cur, dWih1, dWhh1,
                                             nullptr, db1,
                                             c1d, h1nxt, XoutT);
    }
    k_finalize<<<64, 256, 0, stream>>>(h0d + (TD & 1) * 16384, h1d + (TD & 1) * 16384,
                                       c0d, c1d, out);
    k_logits<<<dim3(250, 16), 256, 0, stream>>>(Xout, Wt, out_b, out);
}

// Round 2
// 4790.935 us; speedup vs baseline: 5.0540x; 5.0540x over previous
//
#include <hip/hip_runtime.h>
#include <hip/hip_bf16.h>

typedef __bf16 bf16x8 __attribute__((ext_vector_type(8)));
typedef float f32x4 __attribute__((ext_vector_type(4)));

#define DEV static __device__ __forceinline__

constexpr int Bq = 32, Sq = 128, Tq = 64, Eq = 256, Hq = 512, Vq = 32000;
constexpr int G4 = 2048;          // 4*H
constexpr int TD = 63;            // decode steps (T-1)
constexpr int KOUT = 1280;        // 2H + E
constexpr float SQRTE = 16.0f;    // sqrt(256)

DEV float sigf(float x) { return 1.0f / (1.0f + __expf(-x)); }
DEV float tanh_fast(float x) {
    float ax = fabsf(x);
    float t = __expf(-2.f * ax);
    float r = (1.f - t) / (1.f + t);
    return x < 0.f ? -r : r;
}

// ============ embeddings (bf16 out) ============
__global__ __launch_bounds__(256) void k_embed_src(const int* __restrict__ tok,
                                                   const float* __restrict__ emb,
                                                   __hip_bfloat16* __restrict__ x)
{
    int idx = blockIdx.x * 256 + threadIdx.x;     // S*B*E = 1048576
    int e = idx & (Eq - 1);
    int r = idx >> 8;                             // t*32 + b
    int b = r & 31, t = r >> 5;
    x[idx] = __float2bfloat16(emb[(size_t)tok[b * Sq + t] * Eq + e] * SQRTE);
}

__global__ __launch_bounds__(256) void k_embed_tgt(const int* __restrict__ tok,
                                                   const float* __restrict__ emb,
                                                   __hip_bfloat16* __restrict__ embt,
                                                   __hip_bfloat16* __restrict__ Xout)
{
    int idx = blockIdx.x * 256 + threadIdx.x;     // 63*32*256 = 516096
    int e = idx & (Eq - 1);
    int r = idx >> 8;                             // t*32 + b
    int b = r & 31, t = r >> 5;
    float v = fmaxf(0.f, emb[(size_t)tok[b * Tq + t] * Eq + e] * SQRTE);
    embt[idx] = __float2bfloat16(v);
    Xout[(size_t)r * KOUT + 1024 + e] = __float2bfloat16(v);
}

// ============ transpose + cast W (K x N) -> Wt (N x K) bf16 ============
__global__ __launch_bounds__(256) void k_transpose_bf16(const float* __restrict__ W,
                                                        __hip_bfloat16* __restrict__ Wt,
                                                        int K, int N)
{
    __shared__ float tile[32][33];
    int nb = blockIdx.x * 32, kb = blockIdx.y * 32;
    int c = threadIdx.x & 31, r4 = threadIdx.x >> 5;   // 8 rows per pass
    for (int i = 0; i < 32; i += 8)
        tile[r4 + i][c] = W[(size_t)(kb + r4 + i) * N + nb + c];
    __syncthreads();
    for (int i = 0; i < 32; i += 8) {
        int rr = r4 + i;
        Wt[(size_t)(nb + rr) * K + kb + c] = __float2bfloat16(tile[c][rr]);
    }
}

// ============ MFMA helpers (recurrent path, K=512, A=32x512) ============
// LDS A layout: 32 rows x 512 bf16, 16B chunks XOR-swizzled by (row&7).
DEV void stage_A(const __hip_bfloat16* A, __bf16* As) {
    int tx = threadIdx.x;
#pragma unroll
    for (int p = 0; p < 8; ++p) {
        int c = tx + p * 256;                  // 2048 chunks of 8 bf16
        int row = c >> 6, kc = c & 63;
        uint4 v = *(const uint4*)((const unsigned short*)A + row * 512 + kc * 8);
        int kd = kc ^ (row & 7);
        *(uint4*)(As + row * 512 + kd * 8) = v;
    }
}

// acc[2] covers batch rows 0-15 / 16-31 for one 16-col tile at colB.
DEV void mfma_pass(const __bf16* As, const unsigned short* BT, int colB,
                   int kg, int fr, f32x4* acc) {
    const unsigned short* bp = BT + (size_t)colB * 512 + kg * 8;
    int f7 = fr & 7;
#pragma unroll
    for (int k0 = 0; k0 < 512; k0 += 32) {
        int cidx = ((k0 >> 3) | kg) ^ f7;
        bf16x8 bfv = *(const bf16x8*)(bp + k0);
        bf16x8 af0 = *(const bf16x8*)(As + fr * 512 + cidx * 8);
        bf16x8 af1 = *(const bf16x8*)(As + (16 + fr) * 512 + cidx * 8);
        acc[0] = __builtin_amdgcn_mfma_f32_16x16x32_bf16(af0, bfv, acc[0], 0, 0, 0);
        acc[1] = __builtin_amdgcn_mfma_f32_16x16x32_bf16(af1, bfv, acc[1], 0, 0, 0);
    }
}

// Full recurrent step body: gates(32x2048) = A0@B0T [+ A1@B1T] + xpart/bias,
// cell update, h writes. Block covers j-tile of 16; wave w = gate w.
DEV void rec_core(const __hip_bfloat16* A0, const __hip_bfloat16* B0T,
                  const __hip_bfloat16* A1, const __hip_bfloat16* B1T,
                  const __hip_bfloat16* xpart, const float* bias,
                  float* cbuf, float* hf, __hip_bfloat16* hb,
                  float* ef32, int ef32_stride,
                  __hip_bfloat16* ebf16, int ebf16_stride,
                  int j0, __bf16* As0, __bf16* As1)
{
    stage_A(A0, As0);
    if (A1) stage_A(A1, As1);
    __syncthreads();

    int tx = threadIdx.x, w = tx >> 6, lane = tx & 63;
    int fr = lane & 15, kg = lane >> 4;
    int colB = w * 512 + j0 + fr;

    f32x4 acc[2];
    acc[0] = (f32x4){0.f, 0.f, 0.f, 0.f};
    acc[1] = (f32x4){0.f, 0.f, 0.f, 0.f};
    mfma_pass(As0, (const unsigned short*)B0T, colB, kg, fr, acc);
    if (B1T) mfma_pass(As1, (const unsigned short*)B1T, colB, kg, fr, acc);

    __syncthreads();                       // all LDS reads done; alias As0 as gbuf
    float* gbuf = (float*)As0;             // [4][32][16]
    float* gw = gbuf + w * 512;
#pragma unroll
    for (int m = 0; m < 2; ++m)
#pragma unroll
        for (int q = 0; q < 4; ++q)
            gw[(m * 16 + kg * 4 + q) * 16 + fr] = acc[m][q];
    __syncthreads();

    int idx = tx;
#pragma unroll
    for (int r = 0; r < 2; ++r, idx += 256) {
        int b = idx >> 4, jj = idx & 15, j = j0 + jj;
        float gi = gbuf[0 * 512 + b * 16 + jj];
        float gf = gbuf[1 * 512 + b * 16 + jj];
        float gg = gbuf[2 * 512 + b * 16 + jj];
        float go = gbuf[3 * 512 + b * 16 + jj];
        if (xpart) {
            gi += __bfloat162float(xpart[b * 2048 + j]);
            gf += __bfloat162float(xpart[b * 2048 + 512 + j]);
            gg += __bfloat162float(xpart[b * 2048 + 1024 + j]);
            go += __bfloat162float(xpart[b * 2048 + 1536 + j]);
        }
        if (bias) {
            gi += bias[j]; gf += bias[512 + j];
            gg += bias[1024 + j]; go += bias[1536 + j];
        }
        int ci = b * 512 + j;
        float cc = cbuf[ci];
        float cn = sigf(gf) * cc + sigf(gi) * tanh_fast(gg);
        cbuf[ci] = cn;
        float ho = sigf(go) * tanh_fast(cn);
        hf[ci] = ho;
        hb[ci] = __float2bfloat16(ho);
        if (ef32)  ef32[b * ef32_stride + j] = ho;
        if (ebf16) ebf16[b * ebf16_stride + j] = __float2bfloat16(ho);
    }
}

// decoder gates kernel (grid 32)
__global__ __launch_bounds__(256) void k_rec(
    const __hip_bfloat16* __restrict__ A0, const __hip_bfloat16* __restrict__ B0T,
    const __hip_bfloat16* __restrict__ A1, const __hip_bfloat16* __restrict__ B1T,
    const __hip_bfloat16* __restrict__ xpart, const float* __restrict__ bias,
    float* __restrict__ cbuf, float* __restrict__ hf, __hip_bfloat16* __restrict__ hb,
    __hip_bfloat16* __restrict__ ebf16, int ebf16_stride)
{
    __shared__ __align__(16) __bf16 As0[32 * 512];
    __shared__ __align__(16) __bf16 As1[32 * 512];
    rec_core(A0, B0T, A1, B1T, xpart, bias, cbuf, hf, hb,
             nullptr, 0, ebf16, ebf16_stride, blockIdx.x * 16, As0, As1);
}

// encoder dual-layer step (grid 64: 0-31 layer0 step t, 32-63 layer1 step t-1)
__global__ __launch_bounds__(256) void k_enc2(int t,
    const __hip_bfloat16* __restrict__ X0b,
    const __hip_bfloat16* __restrict__ eWhh0T, const __hip_bfloat16* __restrict__ eWih1T,
    const __hip_bfloat16* __restrict__ eWhh1T, const float* __restrict__ eb1,
    __hip_bfloat16* __restrict__ h0b, __hip_bfloat16* __restrict__ h1b,
    float* __restrict__ h0f, float* __restrict__ h1f,
    float* __restrict__ c0, float* __restrict__ c1,
    __hip_bfloat16* __restrict__ ys0b,
    float* __restrict__ encf, __hip_bfloat16* __restrict__ encb)
{
    __shared__ __align__(16) __bf16 As0[32 * 512];
    __shared__ __align__(16) __bf16 As1[32 * 512];
    bool lay1 = blockIdx.x >= 32;
    int j0 = (blockIdx.x & 31) * 16;
    if (!lay1) {
        if (t >= 128) return;
        rec_core(h0b + (t & 1) * 16384, eWhh0T, nullptr, nullptr,
                 X0b + (size_t)t * 32 * 2048, nullptr,
                 c0, h0f, h0b + ((t + 1) & 1) * 16384,
                 nullptr, 0, ys0b + (size_t)t * 16384, 512, j0, As0, As1);
    } else {
        if (t < 1) return;
        int s = t - 1;
        rec_core(ys0b + (size_t)s * 16384, eWih1T,
                 h1b + (s & 1) * 16384, eWhh1T,
                 nullptr, eb1,
                 c1, h1f, h1b + ((s + 1) & 1) * 16384,
                 encf + s * 512, 128 * 512, encb + s * 512, 128 * 512, j0, As0, As1);
    }
}

// ============ attention: aq = relu(coal(h)) @ Wq + attn_b (grid 8) ============
__global__ __launch_bounds__(256) void k_attnq(
    const float* __restrict__ h0f, const float* __restrict__ h1f,
    const __hip_bfloat16* __restrict__ WqT, const float* __restrict__ attn_b,
    const float* __restrict__ coal_w, const float* __restrict__ coal_b,
    float* __restrict__ aq)
{
    __shared__ __align__(16) __bf16 Qs[32 * 512];
    int tx = threadIdx.x;
    float cw0 = coal_w[0], cw1 = coal_w[1], cb = coal_b[0];
    for (int idx = tx; idx < 16384; idx += 256) {
        int b = idx >> 9, j = idx & 511;
        int p = b * 1024 + 2 * j;
        float v0 = (p < 16384) ? h0f[p] : h1f[p - 16384];
        float v1 = (p + 1 < 16384) ? h0f[p + 1] : h1f[p + 1 - 16384];
        float q = fmaxf(0.f, v0 * cw0 + v1 * cw1 + cb);
        int kc = j >> 3, kd = kc ^ (b & 7);
        Qs[b * 512 + kd * 8 + (j & 7)] = __float2bfloat16(q);
    }
    __syncthreads();
    int w = tx >> 6, lane = tx & 63, fr = lane & 15, kg = lane >> 4;
    int col = blockIdx.x * 64 + w * 16 + fr;
    f32x4 acc[2];
    acc[0] = (f32x4){0.f, 0.f, 0.f, 0.f};
    acc[1] = (f32x4){0.f, 0.f, 0.f, 0.f};
    mfma_pass(Qs, (const unsigned short*)WqT, col, kg, fr, acc);
    float ab = attn_b[col];
#pragma unroll
    for (int m = 0; m < 2; ++m)
#pragma unroll
        for (int q = 0; q < 4; ++q)
            aq[(m * 16 + kg * 4 + q) * 512 + col] = acc[m][q] + ab;
}

// ============ attention: scores + softmax + wctx (grid 32, one b per block) ============
__global__ __launch_bounds__(256) void k_attnsc(
    const float* __restrict__ aq, const float* __restrict__ v_w,
    const int* __restrict__ src_tok,
    const float* __restrict__ enc_proj, const float* __restrict__ enc_outf,
    __hip_bfloat16* __restrict__ wctxb, __hip_bfloat16* __restrict__ XoutT)
{
    __shared__ float aqs[512];
    __shared__ float vws[512];
    __shared__ float sc[128];
    int b = blockIdx.x;
    int tx = threadIdx.x;
    for (int i = tx; i < 512; i += 256) { aqs[i] = aq[b * 512 + i]; vws[i] = v_w[i]; }
    __syncthreads();

    int s = tx >> 1, half = tx & 1;
    const float* ep = enc_proj + ((size_t)(b * 128 + s)) * 512 + half * 256;
    float a0 = 0.f, a1 = 0.f, a2 = 0.f, a3 = 0.f;
#pragma unroll 8
    for (int ii = 0; ii < 256; ii += 4) {
        float4 f = *(const float4*)(ep + ii);
        int ib = half * 256 + ii;
        a0 += tanh_fast(f.x + aqs[ib])     * vws[ib];
        a1 += tanh_fast(f.y + aqs[ib + 1]) * vws[ib + 1];
        a2 += tanh_fast(f.z + aqs[ib + 2]) * vws[ib + 2];
        a3 += tanh_fast(f.w + aqs[ib + 3]) * vws[ib + 3];
    }
    float p = (a0 + a1) + (a2 + a3);
    p += __shfl_xor(p, 1, 64);
    if (half == 0) sc[s] = (src_tok[b * 128 + s] != 1) ? p : -1e10f;
    __syncthreads();

    if (tx < 64) {
        float m1 = fmaxf(sc[tx], sc[tx + 64]);
#pragma unroll
        for (int o = 32; o > 0; o >>= 1) m1 = fmaxf(m1, __shfl_down(m1, o, 64));
        m1 = __shfl(m1, 0, 64);
        float e0 = __expf(sc[tx] - m1), e1 = __expf(sc[tx + 64] - m1);
        float ss = e0 + e1;
#pragma unroll
        for (int o = 32; o > 0; o >>= 1) ss += __shfl_down(ss, o, 64);
        ss = __shfl(ss, 0, 64);
        float inv = 1.0f / ss;
        sc[tx] = e0 * inv; sc[tx + 64] = e1 * inv;
    }
    __syncthreads();

#pragma unroll
    for (int rr = 0; rr < 2; ++rr) {
        int i = tx + rr * 256;
        const float* eo = enc_outf + (size_t)b * 65536 + i;
        float w0 = 0.f, w1 = 0.f, w2 = 0.f, w3 = 0.f;
#pragma unroll 8
        for (int s2 = 0; s2 < 128; s2 += 4) {
            w0 += sc[s2]     * eo[(s2)     * 512];
            w1 += sc[s2 + 1] * eo[(s2 + 1) * 512];
            w2 += sc[s2 + 2] * eo[(s2 + 2) * 512];
            w3 += sc[s2 + 3] * eo[(s2 + 3) * 512];
        }
        float wv = (w0 + w1) + (w2 + w3);
        wctxb[b * 512 + i] = __float2bfloat16(wv);
        XoutT[(size_t)b * KOUT + 512 + i] = __float2bfloat16(wv);
    }
}

// ============ generic MFMA GEMM: C(MxN) = A(MxK)bf16 @ BT(NxK)bf16 + bias ============
__global__ __launch_bounds__(256) void k_mfma(
    const __hip_bfloat16* __restrict__ A, const __hip_bfloat16* __restrict__ BT,
    const float* __restrict__ bias, float* __restrict__ Cf,
    __hip_bfloat16* __restrict__ Cb, int M, int N, int K)
{
    __shared__ __bf16 As[128][72];
    __shared__ __bf16 Bs[128][72];
    const unsigned short* Aw = (const unsigned short*)A;
    const unsigned short* Bw = (const unsigned short*)BT;
    int n0 = blockIdx.x * 128, m0 = blockIdx.y * 128;
    int tx = threadIdx.x;
    int w = tx >> 6, lane = tx & 63;
    int wm = (w >> 1) * 64, wn = (w & 1) * 64;
    int fr = lane & 15, kg = lane >> 4;
    f32x4 acc[4][4];
#pragma unroll
    for (int mi = 0; mi < 4; mi++)
#pragma unroll
        for (int ni = 0; ni < 4; ni++) acc[mi][ni] = (f32x4){0.f, 0.f, 0.f, 0.f};

    for (int k0 = 0; k0 < K; k0 += 64) {
        __syncthreads();
#pragma unroll
        for (int p = 0; p < 4; p++) {
            int ch = tx + p * 256;
            int r = ch >> 3, cc = (ch & 7) * 8;
            uint4 va = {0u, 0u, 0u, 0u};
            int m = m0 + r;
            if (m < M) va = *(const uint4*)(Aw + (size_t)m * K + k0 + cc);
            *(uint4*)(&As[r][cc]) = va;
            uint4 vb = *(const uint4*)(Bw + (size_t)(n0 + r) * K + k0 + cc);
            *(uint4*)(&Bs[r][cc]) = vb;
        }
        __syncthreads();
#pragma unroll
        for (int kk = 0; kk < 64; kk += 32) {
            bf16x8 af[4], bfv[4];
#pragma unroll
            for (int i = 0; i < 4; i++) {
                af[i]  = *(const bf16x8*)(&As[wm + i * 16 + fr][kk + kg * 8]);
                bfv[i] = *(const bf16x8*)(&Bs[wn + i * 16 + fr][kk + kg * 8]);
            }
#pragma unroll
            for (int mi = 0; mi < 4; mi++)
#pragma unroll
                for (int ni = 0; ni < 4; ni++)
                    acc[mi][ni] = __builtin_amdgcn_mfma_f32_16x16x32_bf16(
                        af[mi], bfv[ni], acc[mi][ni], 0, 0, 0);
        }
    }
#pragma unroll
    for (int ni = 0; ni < 4; ni++) {
        int n = n0 + wn + ni * 16 + fr;
        float bv = bias ? bias[n] : 0.f;
#pragma unroll
        for (int mi = 0; mi < 4; mi++) {
#pragma unroll
            for (int qd = 0; qd < 4; qd++) {
                int R = m0 + wm + mi * 16 + kg * 4 + qd;
                if (R < M) {
                    float v = acc[mi][ni][qd] + bv;
                    if (Cf) Cf[(size_t)R * N + n] = v;
                    else    Cb[(size_t)R * N + n] = __float2bfloat16(v);
                }
            }
        }
    }
}

// ============ small kernels ============
__global__ __launch_bounds__(256) void k_init_dec(
    const float* __restrict__ h0e, const float* __restrict__ h1e,
    const float* __restrict__ c0e, const float* __restrict__ c1e,
    float* __restrict__ h0fd, float* __restrict__ h1fd,
    __hip_bfloat16* __restrict__ h0bd, __hip_bfloat16* __restrict__ h1bd,
    float* __restrict__ c0d, float* __restrict__ c1d)
{
    int idx = blockIdx.x * 256 + threadIdx.x;     // 16384
    float a = h0e[idx], b = h1e[idx];
    h0fd[idx] = a; h1fd[idx] = b;
    h0bd[idx] = __float2bfloat16(a);
    h1bd[idx] = __float2bfloat16(b);
    c0d[idx] = c0e[idx];
    c1d[idx] = c1e[idx];
}

__global__ __launch_bounds__(256) void k_bos(float* __restrict__ out)
{
    int b = blockIdx.y;
    int i = blockIdx.x * 256 + threadIdx.x;       // 32000
    out[(size_t)b * (Tq * Vq) + i] = 2.0f;        // BOS_IDX
}

__global__ __launch_bounds__(256) void k_finalize(
    const float* __restrict__ h0f, const float* __restrict__ h1f,
    const float* __restrict__ c0f, const float* __restrict__ c1f,
    float* __restrict__ out)
{
    int idx = blockIdx.x * 256 + threadIdx.x;     // 16384
    size_t base = (size_t)Bq * Tq * Vq;
    out[base + idx] = h0f[idx];
    out[base + 16384 + idx] = h1f[idx];
    out[base + 32768 + idx] = c0f[idx];
    out[base + 49152 + idx] = c1f[idx];
}

// ============ logits GEMM (scatter epilogue) ============
__global__ __launch_bounds__(256) void k_logits(
    const __hip_bfloat16* __restrict__ A, const __hip_bfloat16* __restrict__ Bt,
    const float* __restrict__ bias, float* __restrict__ out)
{
    __shared__ __bf16 As[128][72];
    __shared__ __bf16 Bs[128][72];
    const unsigned short* Aw = (const unsigned short*)A;
    const unsigned short* Bw = (const unsigned short*)Bt;
    int n0 = blockIdx.x * 128, m0 = blockIdx.y * 128;
    int tx = threadIdx.x;
    int w = tx >> 6, lane = tx & 63;
    int wm = (w >> 1) * 64, wn = (w & 1) * 64;
    int fr = lane & 15, kg = lane >> 4;
    f32x4 acc[4][4];
#pragma unroll
    for (int mi = 0; mi < 4; mi++)
#pragma unroll
        for (int ni = 0; ni < 4; ni++) acc[mi][ni] = (f32x4){0.f, 0.f, 0.f, 0.f};

    for (int k0 = 0; k0 < 1280; k0 += 64) {
        __syncthreads();
#pragma unroll
        for (int p = 0; p < 4; p++) {
            int ch = tx + p * 256;
            int r = ch >> 3, cc = (ch & 7) * 8;
            uint4 va = {0u, 0u, 0u, 0u};
            int m = m0 + r;
            if (m < 2016) va = *(const uint4*)(Aw + (size_t)m * 1280 + k0 + cc);
            *(uint4*)(&As[r][cc]) = va;
            uint4 vb = *(const uint4*)(Bw + (size_t)(n0 + r) * 1280 + k0 + cc);
            *(uint4*)(&Bs[r][cc]) = vb;
        }
        __syncthreads();
#pragma unroll
        for (int kk = 0; kk < 64; kk += 32) {
            bf16x8 af[4], bfv[4];
#pragma unroll
            for (int i = 0; i < 4; i++) {
                af[i]  = *(const bf16x8*)(&As[wm + i * 16 + fr][kk + kg * 8]);
                bfv[i] = *(const bf16x8*)(&Bs[wn + i * 16 + fr][kk + kg * 8]);
            }
#pragma unroll
            for (int mi = 0; mi < 4; mi++)
#pragma unroll
                for (int ni = 0; ni < 4; ni++)
                    acc[mi][ni] = __builtin_amdgcn_mfma_f32_16x16x32_bf16(
                        af[mi], bfv[ni], acc[mi][ni], 0, 0, 0);
        }
    }
#pragma unroll
    for (int ni = 0; ni < 4; ni++) {
        int n = n0 + wn + ni * 16 + fr;
        float bv = bias[n];
#pragma unroll
        for (int mi = 0; mi < 4; mi++) {
#pragma unroll
            for (int qd = 0; qd < 4; qd++) {
                int R = m0 + wm + mi * 16 + kg * 4 + qd;
                if (R < 2016) {
                    int bb = R & 31, ts = R >> 5;
                    out[(size_t)bb * (Tq * Vq) + (size_t)(ts + 1) * Vq + n] =
                        acc[mi][ni][qd] + bv;
                }
            }
        }
    }
}

// ============ launcher ============
extern "C" void kernel_launch(void* const* d_in, const int* in_sizes, int n_in,
                              void* d_out, int out_size, void* d_ws, size_t ws_size,
                              hipStream_t stream)
{
    (void)in_sizes; (void)n_in; (void)out_size; (void)ws_size;
    const int*   src_tok = (const int*)  d_in[0];
    const int*   tgt_tok = (const int*)  d_in[1];
    const float* src_emb = (const float*)d_in[2];
    const float* tgt_emb = (const float*)d_in[3];
    const float* eWih0   = (const float*)d_in[4];
    const float* eWhh0   = (const float*)d_in[5];
    const float* eb0     = (const float*)d_in[6];
    const float* eWih1   = (const float*)d_in[7];
    const float* eWhh1   = (const float*)d_in[8];
    const float* eb1     = (const float*)d_in[9];
    const float* dWih0   = (const float*)d_in[10];
    const float* dWhh0   = (const float*)d_in[11];
    const float* db0     = (const float*)d_in[12];
    const float* dWih1   = (const float*)d_in[13];
    const float* dWhh1   = (const float*)d_in[14];
    const float* db1     = (const float*)d_in[15];
    const float* attn_W  = (const float*)d_in[16];
    const float* attn_b  = (const float*)d_in[17];
    const float* v_w     = (const float*)d_in[18];
    const float* coal_w  = (const float*)d_in[19];
    const float* coal_b  = (const float*)d_in[20];
    const float* out_W   = (const float*)d_in[21];
    const float* out_b   = (const float*)d_in[22];
    float* out = (float*)d_out;

    char* ws = (char*)d_ws;
    size_t off = 0;
    auto alloc = [&](size_t bytes) -> char* {
        char* p = ws + off;
        off += (bytes + 255) & ~(size_t)255;
        return p;
    };
    typedef __hip_bfloat16 BF;
    BF* X0b     = (BF*)alloc(4096ull * 2048 * 2);
    BF* Xembb   = (BF*)alloc(2016ull * 2048 * 2);
    BF* x_srcb  = (BF*)alloc(4096ull * 256 * 2);
    BF* embtb   = (BF*)alloc(2016ull * 256 * 2);
    BF* ys0b    = (BF*)alloc(128ull * 16384 * 2);
    float* enc_outf = (float*)alloc(4096ull * 512 * 4);
    BF* enc_outb    = (BF*)alloc(4096ull * 512 * 2);
    float* enc_proj = (float*)alloc(4096ull * 512 * 4);
    float* aq       = (float*)alloc(16384ull * 4);
    BF* wctxb       = (BF*)alloc(16384ull * 2);
    BF* Xout        = (BF*)alloc(2016ull * 1280 * 2);
    BF* Wt          = (BF*)alloc(32000ull * 1280 * 2);
    BF* eWhh0T  = (BF*)alloc(2048ull * 512 * 2);
    BF* eWih1T  = (BF*)alloc(2048ull * 512 * 2);
    BF* eWhh1T  = (BF*)alloc(2048ull * 512 * 2);
    BF* dWih0wT = (BF*)alloc(2048ull * 512 * 2);
    BF* dWhh0T  = (BF*)alloc(2048ull * 512 * 2);
    BF* dWih1T  = (BF*)alloc(2048ull * 512 * 2);
    BF* dWhh1T  = (BF*)alloc(2048ull * 512 * 2);
    BF* eWih0T  = (BF*)alloc(2048ull * 256 * 2);
    BF* dWih0eT = (BF*)alloc(2048ull * 256 * 2);
    BF* WqT     = (BF*)alloc(512ull * 512 * 2);
    BF* WeT     = (BF*)alloc(512ull * 512 * 2);
    BF* h0b_e   = (BF*)alloc(2ull * 16384 * 2);
    BF* h1b_e   = (BF*)alloc(2ull * 16384 * 2);
    float* h0f_e = (float*)alloc(16384ull * 4);
    float* h1f_e = (float*)alloc(16384ull * 4);
    float* c0e   = (float*)alloc(16384ull * 4);
    float* c1e   = (float*)alloc(16384ull * 4);
    float* h0fd  = (float*)alloc(2ull * 16384 * 4);
    float* h1fd  = (float*)alloc(2ull * 16384 * 4);
    BF* h0bd     = (BF*)alloc(2ull * 16384 * 2);
    BF* h1bd     = (BF*)alloc(2ull * 16384 * 2);
    float* c0d   = (float*)alloc(16384ull * 4);
    float* c1d   = (float*)alloc(16384ull * 4);

    hipMemsetAsync(h0b_e, 0, 2 * 16384 * 2, stream);
    hipMemsetAsync(h1b_e, 0, 2 * 16384 * 2, stream);
    hipMemsetAsync(c0e, 0, 16384 * 4, stream);
    hipMemsetAsync(c1e, 0, 16384 * 4, stream);

    // embeddings
    k_embed_src<<<4096, 256, 0, stream>>>(src_tok, src_emb, x_srcb);
    k_embed_tgt<<<2016, 256, 0, stream>>>(tgt_tok, tgt_emb, embtb, Xout);

    // weight transposes (f32 -> bf16, N-major)
    k_transpose_bf16<<<dim3(64, 16), 256, 0, stream>>>(eWhh0, eWhh0T, 512, 2048);
    k_transpose_bf16<<<dim3(64, 16), 256, 0, stream>>>(eWih1, eWih1T, 512, 2048);
    k_transpose_bf16<<<dim3(64, 16), 256, 0, stream>>>(eWhh1, eWhh1T, 512, 2048);
    k_transpose_bf16<<<dim3(64, 16), 256, 0, stream>>>(dWih0 + 256 * 2048, dWih0wT, 512, 2048);
    k_transpose_bf16<<<dim3(64, 16), 256, 0, stream>>>(dWhh0, dWhh0T, 512, 2048);
    k_transpose_bf16<<<dim3(64, 16), 256, 0, stream>>>(dWih1, dWih1T, 512, 2048);
    k_transpose_bf16<<<dim3(64, 16), 256, 0, stream>>>(dWhh1, dWhh1T, 512, 2048);
    k_transpose_bf16<<<dim3(64, 8), 256, 0, stream>>>(eWih0, eWih0T, 256, 2048);
    k_transpose_bf16<<<dim3(64, 8), 256, 0, stream>>>(dWih0, dWih0eT, 256, 2048);
    k_transpose_bf16<<<dim3(16, 16), 256, 0, stream>>>(attn_W, WqT, 512, 512);
    k_transpose_bf16<<<dim3(16, 16), 256, 0, stream>>>(attn_W + 512 * 512, WeT, 512, 512);
    k_transpose_bf16<<<dim3(1000, 40), 256, 0, stream>>>(out_W, Wt, 1280, 32000);

    // input-side GEMMs (bf16 out)
    k_mfma<<<dim3(16, 32), 256, 0, stream>>>(x_srcb, eWih0T, eb0, nullptr, X0b, 4096, 2048, 256);
    k_mfma<<<dim3(16, 16), 256, 0, stream>>>(embtb, dWih0eT, db0, nullptr, Xembb, 2016, 2048, 256);
    k_bos<<<dim3(125, 32), 256, 0, stream>>>(out);

    // encoder (software-pipelined layers)
    for (int t = 0; t <= 128; ++t)
        k_enc2<<<64, 256, 0, stream>>>(t, X0b, eWhh0T, eWih1T, eWhh1T, eb1,
                                       h0b_e, h1b_e, h0f_e, h1f_e, c0e, c1e,
                                       ys0b, enc_outf, enc_outb);

    // enc_proj = enc_out @ We (f32 out)
    k_mfma<<<dim3(4, 32), 256, 0, stream>>>(enc_outb, WeT, nullptr, enc_proj, nullptr, 4096, 512, 512);

    k_init_dec<<<64, 256, 0, stream>>>(h0f_e, h1f_e, c0e, c1e,
                                       h0fd, h1fd, h0bd, h1bd, c0d, c1d);

    // decoder
    for (int t = 0; t < TD; ++t) {
        int cur = t & 1, nxt = (t + 1) & 1;
        BF* XoutT = Xout + (size_t)t * 32 * KOUT;
        k_attnq<<<8, 256, 0, stream>>>(h0fd + cur * 16384, h1fd + cur * 16384,
                                       WqT, attn_b, coal_w, coal_b, aq);
        k_attnsc<<<32, 256, 0, stream>>>(aq, v_w, src_tok, enc_proj, enc_outf,
                                         wctxb, XoutT);
        k_rec<<<32, 256, 0, stream>>>(wctxb, dWih0wT,
                                      h0bd + cur * 16384, dWhh0T,
                                      Xembb + (size_t)t * 32 * 2048, nullptr,
                                      c0d, h0fd + nxt * 16384, h0bd + nxt * 16384,
                                      nullptr, 0);
        k_rec<<<32, 256, 0, stream>>>(h0bd + nxt * 16384, dWih1T,
                                      h1bd + cur * 16384, dWhh1T,
                                      nullptr, db1,
                                      c1d, h1fd + nxt * 16384, h1bd + nxt * 16384,
                                      XoutT, KOUT);
    }
    k_finalize<<<64, 256, 0, stream>>>(h0fd + (TD & 1) * 16384, h1fd + (TD & 1) * 16384,
                                       c0d, c1d, out);
    k_logits<<<dim3(250, 16), 256, 0, stream>>>(Xout, Wt, out_b, out);
}